// Round 4
// baseline (599.502 us; speedup 1.0000x reference)
//
#include <hip/hip_runtime.h>
#include <cmath>

#define BB  1024
#define TT  128
#define HH1 512
#define HH2 256
#define CC  18

// d_ws layout (byte offsets)
#define WS_DIG   0ull             // W2 digits: 8x4x16x2x32x16 i8 = 512 KB
#define WS_W3D   524288ull        // W3 digits LDS image: 32 KB
#define WS_MASK  557056ull        // s1 masks[row][chunk4][word8][t32] ull = 8 MB
#define WS_MASK2 8945664ull       // s2 masks[stripe][t][row] u32 = 4 MB
#define WS_D3    13139968ull      // D3[t][row][c<18] fp32 = 9.4 MB (end ~22.6 MB)

typedef int  v4i  __attribute__((ext_vector_type(4)));
typedef int  v16i __attribute__((ext_vector_type(16)));
typedef unsigned long long ull;

__device__ __forceinline__ v4i expand_bits(unsigned bits) {
  v4i a;
  a.x = (int)((( bits        & 15u) * 0x204081u) & 0x01010101u);
  a.y = (int)((((bits >>  4) & 15u) * 0x204081u) & 0x01010101u);
  a.z = (int)((((bits >>  8) & 15u) * 0x204081u) & 0x01010101u);
  a.w = (int)((((bits >> 12) & 15u) * 0x204081u) & 0x01010101u);
  return a;
}

// ---- merged prep: W2 digits | W3 digits | layer-1 spike masks.
// bid < 2048: W2 fp32 -> 4 signed-i8 digit planes of llrint(w*2^32), laid out
//   [stripe(8)][d(4)][s(16)][h(2)][n(32)][j(16)]; h1=s*32+h*16+j, h2=st*32+n.
// bid < 2176: W3 digits LDS image [d(4)][c8(8)][h(2)][col(32)][j(16)], 32 KB.
// else      : bit-exact layer-1 scan; masks layout [row][chunk(4)][word(8)][t(32)].
__global__ __launch_bounds__(256) void prep_all(const float* __restrict__ W2,
    const float* __restrict__ W3, const float* __restrict__ x,
    const float* __restrict__ W1, const float* __restrict__ b1,
    signed char* __restrict__ dig, signed char* __restrict__ w3dig,
    ull* __restrict__ masks)
{
  __shared__ float xrow[TT];
  const int bid = blockIdx.x, tid = threadIdx.x;

  if (bid < 2048) {
    int i = bid * 256 + tid;                      // [0, 524288)
    int j = i & 15, n = (i >> 4) & 31, h = (i >> 9) & 1;
    int s = (i >> 10) & 15, d = (i >> 14) & 3, st = i >> 16;
    int h1 = s * 32 + h * 16 + j;
    int h2 = st * 32 + n;
    float w = W2[h2 * HH1 + h1];
    long long ll = llrint((double)w * 4294967296.0);
    int v = (int)ll;
    signed char d0 = (signed char)(v & 255); v = (v - d0) >> 8;
    signed char d1 = (signed char)(v & 255); v = (v - d1) >> 8;
    signed char d2 = (signed char)(v & 255); v = (v - d2) >> 8;
    signed char d3 = (signed char)v;
    dig[i] = (d == 0) ? d0 : (d == 1) ? d1 : (d == 2) ? d2 : d3;
    return;
  }
  if (bid < 2176) {
    int i = (bid - 2048) * 256 + tid;             // [0, 32768)
    int j = i & 15, col = (i >> 4) & 31, h = (i >> 9) & 1;
    int c8 = (i >> 10) & 7, d = (i >> 13) & 3;
    int h2 = c8 * 32 + h * 16 + j;
    float w = (col < CC) ? W3[col * HH2 + h2] : 0.0f;
    long long ll = llrint((double)w * 4294967296.0);
    int v = (int)ll;
    signed char d0 = (signed char)(v & 255); v = (v - d0) >> 8;
    signed char d1 = (signed char)(v & 255); v = (v - d1) >> 8;
    signed char d2 = (signed char)(v & 255); v = (v - d2) >> 8;
    signed char d3 = (signed char)v;
    w3dig[i] = (d == 0) ? d0 : (d == 1) ? d1 : (d == 2) ? d2 : d3;
    return;
  }

  // ---- layer-1 scan, one block per batch row
  const int row = bid - 2176, wv = tid >> 6, lane = tid & 63;
  for (int i = tid; i < TT; i += 256) xrow[i] = x[row * TT + i];
  const float w1a = W1[tid], w1b = W1[tid + 256];
  const float b1a = b1[tid], b1b = b1[tid + 256];
  float v1a = 0.f, v1b = 0.f;
  __syncthreads();
  for (int t = 0; t < TT; ++t) {
    float xt = xrow[t];
    float iA = __fadd_rn(__fmul_rn(xt, w1a), b1a);
    v1a = __fadd_rn(v1a, iA);
    bool sA = (v1a >= 1.0f);  v1a = sA ? (v1a - 1.0f) : v1a;
    float iB = __fadd_rn(__fmul_rn(xt, w1b), b1b);
    v1b = __fadd_rn(v1b, iB);
    bool sB = (v1b >= 1.0f);  v1b = sB ? (v1b - 1.0f) : v1b;
    ull mA = __ballot(sA);
    ull mB = __ballot(sB);
    if (lane == 0) {
      // element = row*1024 + (t>>5)*256 + word*32 + (t&31)
      ull* p = masks + (size_t)row * 1024 + (size_t)(t >> 5) * 256 + (t & 31);
      p[(size_t)wv * 32]       = mA;              // word wv    : h1 [64wv, +64)
      p[(size_t)(4 + wv) * 32] = mB;              // word 4+wv  : h1 [256+64wv, +64)
    }
  }
}

// ---- fused layer 2, t-as-M, ONE tile per wave -> 4 waves/SIMD.
// Block = 512 thr (8 waves), LDS = Bl (64 KB) -> 2 blocks/CU; acc = 64 regs
// (one 32t x 32col tile, 4 digit planes) keeps total regs <= 128 so all 16
// waves/CU are resident. Wave wv owns batch row rowgrp*8+wv, all 128 t.
// Per 32-t chunk: A rows are timesteps (tp1 permutation: lane's fold reg r
// holds t = tb + r + 16*half). GEMM s-loop (4 ds_read_b128 + 1 expand +
// 4 MFMA per s, setprio(1) wrapped) -> fold to d[16] -> in-register v2 scan
// (lo lanes t 0..15, shfl_xor(32), hi lanes t 16..31, shfl back). With 4
// independent waves/SIMD, MFMA / VALU / LDS phases of different waves
// overlap organically (no barriers in the main loop).
__global__ __launch_bounds__(512, 4) void phase_gemmscan(
    const signed char* __restrict__ Bd, const ull* __restrict__ masks,
    const float* __restrict__ b2, unsigned* __restrict__ masks2)
{
  __shared__ __align__(16) signed char Bl[65536];

  const int bid = blockIdx.x;
  const int rowgrp = bid & 127, stripe = bid >> 7; // same rows -> same XCD
  const int tid = threadIdx.x, lane = tid & 63, wv = tid >> 6;
  const int half = lane >> 5, l31 = lane & 31;

  {
    const uint4* src = (const uint4*)(Bd + (size_t)stripe * 65536);
    uint4* dst = (uint4*)Bl;
#pragma unroll
    for (int i = 0; i < 8; ++i) dst[tid + 512 * i] = src[tid + 512 * i];
  }

  const signed char* bbase = Bl + half * 512 + l31 * 16;
  const float b2r = b2[stripe * 32 + l31];
  const unsigned hsh = half * 16;
  // A-row l31 -> timestep within chunk (fold reg r = t tb+r+16*half)
  const int tp1 = (l31 & 3) + ((l31 >> 3) << 2) + ((l31 & 4) ? 16 : 0);

  const int row = rowgrp * 8 + wv;
  const ull* mb = masks + (size_t)row * 1024;
  unsigned* m2t = masks2 + (size_t)stripe * (TT * BB) + row;

  float v2 = 0.f;                                  // canonical state in lo half
  __syncthreads();                                 // Bl ready (only barrier)

  for (int c = 0; c < 4; ++c) {
    ull w[8];
#pragma unroll
    for (int k = 0; k < 8; ++k) w[k] = mb[c * 256 + k * 32 + tp1];

    v16i acc[4];
#pragma unroll
    for (int d = 0; d < 4; ++d)
      acc[d] = (v16i){0,0,0,0,0,0,0,0,0,0,0,0,0,0,0,0};

    __builtin_amdgcn_s_setprio(1);
#pragma unroll
    for (int s = 0; s < 16; ++s) {
      v4i q0 = *(const v4i*)(bbase + (0 * 16 + s) * 1024);
      v4i q1 = *(const v4i*)(bbase + (1 * 16 + s) * 1024);
      v4i q2 = *(const v4i*)(bbase + (2 * 16 + s) * 1024);
      v4i q3 = *(const v4i*)(bbase + (3 * 16 + s) * 1024);
      unsigned shift = ((s & 1) << 5) + hsh;
      v4i e = expand_bits((unsigned)(w[s >> 1] >> shift) & 0xFFFFu);
      acc[0] = __builtin_amdgcn_mfma_i32_32x32x32_i8(e, q0, acc[0], 0, 0, 0);
      acc[1] = __builtin_amdgcn_mfma_i32_32x32x32_i8(e, q1, acc[1], 0, 0, 0);
      acc[2] = __builtin_amdgcn_mfma_i32_32x32x32_i8(e, q2, acc[2], 0, 0, 0);
      acc[3] = __builtin_amdgcn_mfma_i32_32x32x32_i8(e, q3, acc[3], 0, 0, 0);
    }
    __builtin_amdgcn_s_setprio(0);

    // exact digit fold -> one f32 rounding (bit-identical); accs die here.
    float dv[16];
#pragma unroll
    for (int r = 0; r < 16; ++r) {
      int slo = acc[0][r] + (acc[1][r] << 8);
      int shi = acc[2][r] + (acc[3][r] << 8);
      double ss = fma((double)shi, 65536.0, (double)slo);  // exact
      dv[r] = (float)(ss * 0x1p-32);                       // one rounding
    }

    // ---- in-register v2 scan, exact t order tb..tb+31 for this row.
    const int tb = c * 32;
    // phase 1: lo lanes advance t = tb+r (hi lanes' state preserved)
#pragma unroll
    for (int r = 0; r < 16; ++r) {
      float i2 = __fadd_rn(dv[r], b2r);
      float u  = __fadd_rn(v2, i2);
      bool s2  = (u >= 1.0f);
      float uv = s2 ? (u - 1.0f) : u;
      ull m = __ballot(s2);                        // lo32 = this row's word
      if (!half) v2 = uv;
      if (lane == 0) m2t[(size_t)(tb + r) * BB] = (unsigned)m;
    }
    v2 = __shfl_xor(v2, 32);                       // state -> hi lanes
    // phase 2: hi lanes advance t = tb+16+r
#pragma unroll
    for (int r = 0; r < 16; ++r) {
      float i2 = __fadd_rn(dv[r], b2r);
      float u  = __fadd_rn(v2, i2);
      bool s2  = (u >= 1.0f);
      float uv = s2 ? (u - 1.0f) : u;
      ull m = __ballot(s2);                        // hi32 = this row's word
      if (half) v2 = uv;
      if (lane == 0) m2t[(size_t)(tb + 16 + r) * BB] = (unsigned)(m >> 32);
    }
    v2 = __shfl_xor(v2, 32);                       // state back to lo lanes
  }
}

// ---- layer 3: D3[t] = S2[t] @ W3^T, exact i8 MFMA. Block: 32 rows x 4 t.
// masks2 layout is [stripe][t][row] u32.
__global__ __launch_bounds__(256) void phase_l3(const signed char* __restrict__ W3d,
    const unsigned* __restrict__ masks2, float* __restrict__ D3)
{
  __shared__ __align__(16) signed char Bl[32768];
  const int bid = blockIdx.x;
  const int rowtile = bid & 31, tgrp = bid >> 5;
  const int tid = threadIdx.x, lane = tid & 63, wv = tid >> 6;
  const int half = lane >> 5;
  const int t = tgrp * 4 + wv;
  const int row = rowtile * 32 + (lane & 31);

  {
    const uint4* src = (const uint4*)W3d;
    uint4* dst = (uint4*)Bl;
#pragma unroll
    for (int i = 0; i < 8; ++i) dst[tid + 256 * i] = src[tid + 256 * i];
  }

  unsigned words[8];
  {
    const unsigned* mp = masks2 + (size_t)t * BB + row;
#pragma unroll
    for (int k = 0; k < 8; ++k) words[k] = mp[(size_t)k * (TT * BB)];
  }
  __syncthreads();

  const signed char* bbase = Bl + half * 512 + (lane & 31) * 16;
  v16i acc[4];
#pragma unroll
  for (int d = 0; d < 4; ++d) acc[d] = (v16i){0,0,0,0,0,0,0,0,0,0,0,0,0,0,0,0};

#pragma unroll
  for (int c8 = 0; c8 < 8; ++c8) {
    v4i a = expand_bits((words[c8] >> (half * 16)) & 0xFFFFu);
#pragma unroll
    for (int d = 0; d < 4; ++d) {
      v4i b = *(const v4i*)(bbase + ((d * 8 + c8) * 2) * 512);
      acc[d] = __builtin_amdgcn_mfma_i32_32x32x32_i8(a, b, acc[d], 0, 0, 0);
    }
  }

  const int col = lane & 31;
#pragma unroll
  for (int r = 0; r < 16; ++r) {
    int slo = acc[0][r] + (acc[1][r] << 8);
    int shi = acc[2][r] + (acc[3][r] << 8);
    double ss = fma((double)shi, 65536.0, (double)slo);
    float d3v = (float)(ss * 0x1p-32);
    int rowl = (r & 3) + 8 * (r >> 2) + 4 * half;
    int grow = rowtile * 32 + rowl;
    if (col < CC) D3[((size_t)t * BB + grow) * CC + col] = d3v;
  }
}

// ---- v3/acc scan + output. thread=(row,c); 4-deep prefetch ring; grid 72.
__global__ __launch_bounds__(256) void phase_v3(const float* __restrict__ D3,
    const float* __restrict__ b3, float* __restrict__ out)
{
  int g = blockIdx.x * 256 + threadIdx.x;         // [0, 18432)
  int row = g / CC, c = g - row * CC;
  const float b3r = b3[c];
  float v3 = 0.f, acc = 0.f;
  float buf[4];
#pragma unroll
  for (int p = 0; p < 4; ++p) buf[p] = D3[(size_t)p * (BB * CC) + g];
  for (int t = 0; t < TT; ++t) {
    float d3 = buf[t & 3];
    if (t + 4 < TT) buf[t & 3] = D3[(size_t)(t + 4) * (BB * CC) + g];
    float i3 = __fadd_rn(d3, b3r);
    v3 = __fadd_rn(v3, i3);
    bool s3 = (v3 >= 1.0f);  v3 = s3 ? (v3 - 1.0f) : v3;
    acc = __fadd_rn(acc, s3 ? 1.0f : 0.0f);
  }
  out[g] = acc * (1.0f / TT);
}

extern "C" void kernel_launch(void* const* d_in, const int* in_sizes, int n_in,
                              void* d_out, int out_size, void* d_ws, size_t ws_size,
                              hipStream_t stream)
{
  (void)in_sizes; (void)n_in; (void)out_size; (void)ws_size;
  const float* x  = (const float*)d_in[0];
  const float* W1 = (const float*)d_in[1];
  const float* b1 = (const float*)d_in[2];
  const float* W2 = (const float*)d_in[3];
  const float* b2 = (const float*)d_in[4];
  const float* W3 = (const float*)d_in[5];
  const float* b3 = (const float*)d_in[6];
  // d_in[7] = repeat (structurally 1 for this problem shape)
  float* out = (float*)d_out;
  char*  ws  = (char*)d_ws;

  signed char* dig    = (signed char*)(ws + WS_DIG);
  signed char* w3dig  = (signed char*)(ws + WS_W3D);
  ull*         masks  = (ull*)(ws + WS_MASK);
  unsigned*    masks2 = (unsigned*)(ws + WS_MASK2);
  float*       D3     = (float*)(ws + WS_D3);

  prep_all<<<3200, 256, 0, stream>>>(W2, W3, x, W1, b1, dig, w3dig, masks);
  phase_gemmscan<<<1024, 512, 0, stream>>>(dig, masks, b2, masks2);
  phase_l3<<<1024, 256, 0, stream>>>(w3dig, masks2, D3);
  phase_v3<<<72, 256, 0, stream>>>(D3, b3, out);
}

// Round 5
// 214.784 us; speedup vs baseline: 2.7912x; 2.7912x over previous
//
#include <hip/hip_runtime.h>
#include <cmath>

#define BB  1024
#define TT  128
#define HH1 512
#define HH2 256
#define CC  18

// d_ws layout (byte offsets)
#define WS_DIG   0ull             // W2 digits: 8x4x16x2x32x16 i8 = 512 KB
#define WS_W3D   524288ull        // W3 digits LDS image: 32 KB
#define WS_MASK  557056ull        // s1 masks[row][chunk4][word8][t32] ull = 8 MB
#define WS_MASK2 8945664ull       // s2 masks[stripe][t][row] u32 = 4 MB
#define WS_D3    13139968ull      // D3[t][row][c<18] fp32 = 9.4 MB (end ~22.6 MB)

typedef int  v4i  __attribute__((ext_vector_type(4)));
typedef int  v16i __attribute__((ext_vector_type(16)));
typedef unsigned long long ull;

__device__ __forceinline__ v4i expand_bits(unsigned bits) {
  v4i a;
  a.x = (int)((( bits        & 15u) * 0x204081u) & 0x01010101u);
  a.y = (int)((((bits >>  4) & 15u) * 0x204081u) & 0x01010101u);
  a.z = (int)((((bits >>  8) & 15u) * 0x204081u) & 0x01010101u);
  a.w = (int)((((bits >> 12) & 15u) * 0x204081u) & 0x01010101u);
  return a;
}

// ---- prep: W2 fp32 -> 4 signed-i8 digit planes of llrint(w*2^32), laid out
// [stripe(8)][d(4)][s(16)][h(2)][n(32)][j(16)]; h1 = s*32+h*16+j, h2 = stripe*32+n.
__global__ __launch_bounds__(256) void prep_digits(const float* __restrict__ W2,
                                                   signed char* __restrict__ out)
{
  int i = blockIdx.x * 256 + threadIdx.x;         // [0, 524288)
  int j = i & 15, n = (i >> 4) & 31, h = (i >> 9) & 1;
  int s = (i >> 10) & 15, d = (i >> 14) & 3, st = i >> 16;
  int h1 = s * 32 + h * 16 + j;
  int h2 = st * 32 + n;
  float w = W2[h2 * HH1 + h1];
  long long ll = llrint((double)w * 4294967296.0);
  int v = (int)ll;
  signed char d0 = (signed char)(v & 255); v = (v - d0) >> 8;
  signed char d1 = (signed char)(v & 255); v = (v - d1) >> 8;
  signed char d2 = (signed char)(v & 255); v = (v - d2) >> 8;
  signed char d3 = (signed char)v;
  signed char dig = (d == 0) ? d0 : (d == 1) ? d1 : (d == 2) ? d2 : d3;
  out[i] = dig;
}

// ---- prep W3 digits, LDS image [d(4)][c8(8)][h(2)][col(32)][j(16)], 32 KB.
__global__ __launch_bounds__(256) void prep_w3dig(const float* __restrict__ W3,
                                                  signed char* __restrict__ out)
{
  int i = blockIdx.x * 256 + threadIdx.x;         // [0, 32768)
  int j = i & 15, col = (i >> 4) & 31, h = (i >> 9) & 1;
  int c8 = (i >> 10) & 7, d = (i >> 13) & 3;
  int h2 = c8 * 32 + h * 16 + j;
  float w = (col < CC) ? W3[col * HH2 + h2] : 0.0f;
  long long ll = llrint((double)w * 4294967296.0);
  int v = (int)ll;
  signed char d0 = (signed char)(v & 255); v = (v - d0) >> 8;
  signed char d1 = (signed char)(v & 255); v = (v - d1) >> 8;
  signed char d2 = (signed char)(v & 255); v = (v - d2) >> 8;
  signed char d3 = (signed char)v;
  signed char dig = (d == 0) ? d0 : (d == 1) ? d1 : (d == 2) ? d2 : d3;
  out[i] = dig;
}

// ---- phase A: bit-exact layer-1 spike masks for all (row,t). One block/row.
// masks layout: [row][chunk(4)][word(8)][t32]  (element = row*1024 + c*256 + w*32 + t&31)
__global__ __launch_bounds__(256) void phase_s1(const float* __restrict__ x,
    const float* __restrict__ W1, const float* __restrict__ b1,
    ull* __restrict__ masks)
{
  __shared__ float xrow[TT];
  int row = blockIdx.x, tid = threadIdx.x, wv = tid >> 6, lane = tid & 63;
  for (int i = tid; i < TT; i += 256) xrow[i] = x[row * TT + i];
  const float w1a = W1[tid], w1b = W1[tid + 256];
  const float b1a = b1[tid], b1b = b1[tid + 256];
  float v1a = 0.f, v1b = 0.f;
  __syncthreads();
  for (int t = 0; t < TT; ++t) {
    float xt = xrow[t];
    float iA = __fadd_rn(__fmul_rn(xt, w1a), b1a);
    v1a = __fadd_rn(v1a, iA);
    bool sA = (v1a >= 1.0f);  v1a = sA ? (v1a - 1.0f) : v1a;
    float iB = __fadd_rn(__fmul_rn(xt, w1b), b1b);
    v1b = __fadd_rn(v1b, iB);
    bool sB = (v1b >= 1.0f);  v1b = sB ? (v1b - 1.0f) : v1b;
    ull mA = __ballot(sA);
    ull mB = __ballot(sB);
    if (lane == 0) {
      ull* p = masks + (size_t)row * 1024 + (size_t)(t >> 5) * 256 + (t & 31);
      p[(size_t)wv * 32]       = mA;              // word wv    : h1 [64wv, +64)
      p[(size_t)(4 + wv) * 32] = mB;              // word 4+wv  : h1 [256+64wv, +64)
    }
  }
}

// ---- fused layer 2, t-as-M-dimension: barrier-free main loop (R3 structure).
// Block = 512 thr (8 waves), LDS = Bl only (64 KB). Wave task = 2 adjacent
// batch rows (r1, r2 = r1+1) x all 128 t; 2 tasks per wave (tau).
// Per 32-t chunk: A-tile rows are TIMESTEPS; each q-load feeds BOTH tiles
// (P/Q pairing halves LDS port traffic - load-bearing, do not drop).
// v2 scan fully in-register via shfl_xor(32). 248 regs -> 2 waves/SIMD.
// NEW (R5): the two co-resident waves on each SIMD (wv and wv+4) are
// de-phase-locked by a one-time ~1900-cycle s_sleep stagger on waves 4-7,
// so one wave's MFMA s-loop overlaps its partner's fold+scan VALU burst;
// setprio(1) around the s-loop lets the MFMA-phase wave win issue.
__global__ __launch_bounds__(512, 2) void phase_gemmscan(
    const signed char* __restrict__ Bd, const ull* __restrict__ masks,
    const float* __restrict__ b2, unsigned* __restrict__ masks2)
{
  __shared__ __align__(16) signed char Bl[65536];

  const int bid = blockIdx.x;
  const int rowgrp = bid & 31, stripe = bid >> 5; // same-rowgrp -> same XCD
  const int tid = threadIdx.x, lane = tid & 63, wv = tid >> 6;
  const int half = lane >> 5, l31 = lane & 31;

  {
    const uint4* src = (const uint4*)(Bd + (size_t)stripe * 65536);
    uint4* dst = (uint4*)Bl;
#pragma unroll
    for (int i = 0; i < 8; ++i) dst[tid + 512 * i] = src[tid + 512 * i];
  }

  const signed char* bbase = Bl + half * 512 + l31 * 16;
  const float b2r = b2[stripe * 32 + l31];
  const unsigned hsh = half * 16;

  // A-row i = l31 -> t_local. tile1: lo-half regs get t 0..15 in order.
  const int tp1 = (l31 & 3) + ((l31 >> 3) << 2) + ((l31 & 4) ? 16 : 0);
  const int tp2 = tp1 ^ 16;                       // tile2: inverted halves

  __syncthreads();                                // Bl ready (only barrier)

  // de-phase stagger: waves 4-7 share SIMDs with waves 0-3; offset their
  // streams by ~half a chunk period so MFMA and VALU phases interleave.
  if (wv & 4) {
    __builtin_amdgcn_s_sleep(15);                 // ~960 cyc
    __builtin_amdgcn_s_sleep(15);                 // ~960 cyc
  }

  for (int tau = 0; tau < 2; ++tau) {
    const int pr = wv + 8 * tau;                  // pair 0..15
    const int r1 = rowgrp * 32 + 2 * pr;
    const ull* mb1 = masks + (size_t)r1 * 1024;
    const ull* mb2 = mb1 + 1024;                  // row r1+1
    unsigned* m2t = masks2 + (size_t)stripe * (TT * BB);
    float v2 = 0.f;                               // lo: r1 state, hi: r2 state

    ull wP[8], wQ[8], wPn[8], wQn[8];
#pragma unroll
    for (int k = 0; k < 8; ++k) {
      wP[k] = mb1[k * 32 + tp1];
      wQ[k] = mb2[k * 32 + tp2];
    }

#pragma unroll
    for (int c = 0; c < 4; ++c) {
      if (c < 3) {                                // prefetch next chunk's masks
#pragma unroll
        for (int k = 0; k < 8; ++k) {
          wPn[k] = mb1[(c + 1) * 256 + k * 32 + tp1];
          wQn[k] = mb2[(c + 1) * 256 + k * 32 + tp2];
        }
      }

      v16i aP[4], aQ[4];
#pragma unroll
      for (int d = 0; d < 4; ++d) {
        aP[d] = (v16i){0,0,0,0,0,0,0,0,0,0,0,0,0,0,0,0};
        aQ[d] = (v16i){0,0,0,0,0,0,0,0,0,0,0,0,0,0,0,0};
      }
      __builtin_amdgcn_s_setprio(1);
#pragma unroll
      for (int s = 0; s < 16; ++s) {
        v4i q0 = *(const v4i*)(bbase + (0 * 16 + s) * 1024);
        v4i q1 = *(const v4i*)(bbase + (1 * 16 + s) * 1024);
        v4i q2 = *(const v4i*)(bbase + (2 * 16 + s) * 1024);
        v4i q3 = *(const v4i*)(bbase + (3 * 16 + s) * 1024);
        unsigned shift = ((s & 1) << 5) + hsh;
        v4i eP = expand_bits((unsigned)(wP[s >> 1] >> shift) & 0xFFFFu);
        v4i eQ = expand_bits((unsigned)(wQ[s >> 1] >> shift) & 0xFFFFu);
        aP[0] = __builtin_amdgcn_mfma_i32_32x32x32_i8(eP, q0, aP[0], 0, 0, 0);
        aQ[0] = __builtin_amdgcn_mfma_i32_32x32x32_i8(eQ, q0, aQ[0], 0, 0, 0);
        aP[1] = __builtin_amdgcn_mfma_i32_32x32x32_i8(eP, q1, aP[1], 0, 0, 0);
        aQ[1] = __builtin_amdgcn_mfma_i32_32x32x32_i8(eQ, q1, aQ[1], 0, 0, 0);
        aP[2] = __builtin_amdgcn_mfma_i32_32x32x32_i8(eP, q2, aP[2], 0, 0, 0);
        aQ[2] = __builtin_amdgcn_mfma_i32_32x32x32_i8(eQ, q2, aQ[2], 0, 0, 0);
        aP[3] = __builtin_amdgcn_mfma_i32_32x32x32_i8(eP, q3, aP[3], 0, 0, 0);
        aQ[3] = __builtin_amdgcn_mfma_i32_32x32x32_i8(eQ, q3, aQ[3], 0, 0, 0);
      }
      __builtin_amdgcn_s_setprio(0);

      // exact digit fold -> one f32 rounding (bit-identical).
      // dP[r]: tile1 value at t_local = r + 16*half; dQ[r]: r + 16*(1-half).
      float dP[16], dQ[16];
#pragma unroll
      for (int r = 0; r < 16; ++r) {
        int sloP = aP[0][r] + (aP[1][r] << 8);
        int shiP = aP[2][r] + (aP[3][r] << 8);
        double ssP = fma((double)shiP, 65536.0, (double)sloP);  // exact
        dP[r] = (float)(ssP * 0x1p-32);                         // one rounding
        int sloQ = aQ[0][r] + (aQ[1][r] << 8);
        int shiQ = aQ[2][r] + (aQ[3][r] << 8);
        double ssQ = fma((double)shiQ, 65536.0, (double)sloQ);
        dQ[r] = (float)(ssQ * 0x1p-32);
      }

      // ---- in-register v2 scan of 32 t (exact order t = tb..tb+31)
      const int tb = c * 32;
      // phase 1: lo lanes scan r1 (dP), hi lanes scan r2 (dQ); t = tb + r
#pragma unroll
      for (int r = 0; r < 16; ++r) {
        float val = half ? dQ[r] : dP[r];
        float i2 = __fadd_rn(val, b2r);
        v2 = __fadd_rn(v2, i2);
        bool s2 = (v2 >= 1.0f);  v2 = s2 ? (v2 - 1.0f) : v2;
        ull m = __ballot(s2);                     // lo32: r1 word, hi32: r2
        if (lane == 0)
          *(ull*)(m2t + (size_t)(tb + r) * BB + r1) = m;
      }
      v2 = __shfl_xor(v2, 32);                    // exchange row states
      // phase 2: lo lanes scan r2 (dQ), hi lanes scan r1 (dP); t = tb+16+r
#pragma unroll
      for (int r = 0; r < 16; ++r) {
        float val = half ? dP[r] : dQ[r];
        float i2 = __fadd_rn(val, b2r);
        v2 = __fadd_rn(v2, i2);
        bool s2 = (v2 >= 1.0f);  v2 = s2 ? (v2 - 1.0f) : v2;
        ull m = __ballot(s2);                     // lo32: r2 word, hi32: r1
        if (lane == 0)
          *(ull*)(m2t + (size_t)(tb + 16 + r) * BB + r1) = (m >> 32) | (m << 32);
      }
      v2 = __shfl_xor(v2, 32);                    // restore arrangement

      if (c < 3) {
#pragma unroll
        for (int k = 0; k < 8; ++k) { wP[k] = wPn[k]; wQ[k] = wQn[k]; }
      }
    }
  }
}

// ---- layer 3: D3[t] = S2[t] @ W3^T, exact i8 MFMA. Block: 32 rows x 4 t.
// masks2 layout is [stripe][t][row] u32.
__global__ __launch_bounds__(256) void phase_l3(const signed char* __restrict__ W3d,
    const unsigned* __restrict__ masks2, float* __restrict__ D3)
{
  __shared__ __align__(16) signed char Bl[32768];
  const int bid = blockIdx.x;
  const int rowtile = bid & 31, tgrp = bid >> 5;
  const int tid = threadIdx.x, lane = tid & 63, wv = tid >> 6;
  const int half = lane >> 5;
  const int t = tgrp * 4 + wv;
  const int row = rowtile * 32 + (lane & 31);

  {
    const uint4* src = (const uint4*)W3d;
    uint4* dst = (uint4*)Bl;
#pragma unroll
    for (int i = 0; i < 8; ++i) dst[tid + 256 * i] = src[tid + 256 * i];
  }

  unsigned words[8];
  {
    const unsigned* mp = masks2 + (size_t)t * BB + row;
#pragma unroll
    for (int k = 0; k < 8; ++k) words[k] = mp[(size_t)k * (TT * BB)];
  }
  __syncthreads();

  const signed char* bbase = Bl + half * 512 + (lane & 31) * 16;
  v16i acc[4];
#pragma unroll
  for (int d = 0; d < 4; ++d) acc[d] = (v16i){0,0,0,0,0,0,0,0,0,0,0,0,0,0,0,0};

#pragma unroll
  for (int c8 = 0; c8 < 8; ++c8) {
    v4i a = expand_bits((words[c8] >> (half * 16)) & 0xFFFFu);
#pragma unroll
    for (int d = 0; d < 4; ++d) {
      v4i b = *(const v4i*)(bbase + ((d * 8 + c8) * 2) * 512);
      acc[d] = __builtin_amdgcn_mfma_i32_32x32x32_i8(a, b, acc[d], 0, 0, 0);
    }
  }

  const int col = lane & 31;
#pragma unroll
  for (int r = 0; r < 16; ++r) {
    int slo = acc[0][r] + (acc[1][r] << 8);
    int shi = acc[2][r] + (acc[3][r] << 8);
    double ss = fma((double)shi, 65536.0, (double)slo);
    float d3v = (float)(ss * 0x1p-32);
    int rowl = (r & 3) + 8 * (r >> 2) + 4 * half;
    int grow = rowtile * 32 + rowl;
    if (col < CC) D3[((size_t)t * BB + grow) * CC + col] = d3v;
  }
}

// ---- v3/acc scan + output. thread=(row,c); 4-deep prefetch ring; grid 72.
__global__ __launch_bounds__(256) void phase_v3(const float* __restrict__ D3,
    const float* __restrict__ b3, float* __restrict__ out)
{
  int g = blockIdx.x * 256 + threadIdx.x;         // [0, 18432)
  int row = g / CC, c = g - row * CC;
  const float b3r = b3[c];
  float v3 = 0.f, acc = 0.f;
  float buf[4];
#pragma unroll
  for (int p = 0; p < 4; ++p) buf[p] = D3[(size_t)p * (BB * CC) + g];
  for (int t = 0; t < TT; ++t) {
    float d3 = buf[t & 3];
    if (t + 4 < TT) buf[t & 3] = D3[(size_t)(t + 4) * (BB * CC) + g];
    float i3 = __fadd_rn(d3, b3r);
    v3 = __fadd_rn(v3, i3);
    bool s3 = (v3 >= 1.0f);  v3 = s3 ? (v3 - 1.0f) : v3;
    acc = __fadd_rn(acc, s3 ? 1.0f : 0.0f);
  }
  out[g] = acc * (1.0f / TT);
}

extern "C" void kernel_launch(void* const* d_in, const int* in_sizes, int n_in,
                              void* d_out, int out_size, void* d_ws, size_t ws_size,
                              hipStream_t stream)
{
  (void)in_sizes; (void)n_in; (void)out_size; (void)ws_size;
  const float* x  = (const float*)d_in[0];
  const float* W1 = (const float*)d_in[1];
  const float* b1 = (const float*)d_in[2];
  const float* W2 = (const float*)d_in[3];
  const float* b2 = (const float*)d_in[4];
  const float* W3 = (const float*)d_in[5];
  const float* b3 = (const float*)d_in[6];
  // d_in[7] = repeat (structurally 1 for this problem shape)
  float* out = (float*)d_out;
  char*  ws  = (char*)d_ws;

  signed char* dig    = (signed char*)(ws + WS_DIG);
  signed char* w3dig  = (signed char*)(ws + WS_W3D);
  ull*         masks  = (ull*)(ws + WS_MASK);
  unsigned*    masks2 = (unsigned*)(ws + WS_MASK2);
  float*       D3     = (float*)(ws + WS_D3);

  prep_digits<<<2048, 256, 0, stream>>>(W2, dig);
  prep_w3dig<<<128, 256, 0, stream>>>(W3, w3dig);
  phase_s1<<<1024, 256, 0, stream>>>(x, W1, b1, masks);
  phase_gemmscan<<<256, 512, 0, stream>>>(dig, masks, b2, masks2);
  phase_l3<<<1024, 256, 0, stream>>>(w3dig, masks2, D3);
  phase_v3<<<72, 256, 0, stream>>>(D3, b3, out);
}

// Round 6
// 182.053 us; speedup vs baseline: 3.2930x; 1.1798x over previous
//
#include <hip/hip_runtime.h>
#include <cmath>

#define BB  1024
#define TT  128
#define HH1 512
#define HH2 256
#define CC  18

// d_ws layout (byte offsets)
#define WS_DIG   0ull             // W2 digits: 8x4x16x2x32x16 i8 = 512 KB
#define WS_W3D   524288ull        // W3 digits LDS image: 32 KB
#define WS_MASK  557056ull        // s1 masks[row][chunk4][word8][t32] ull = 8 MB
#define WS_MASK2 8945664ull       // s2 masks[stripe][t][row] u32 = 4 MB
#define WS_D3    13139968ull      // D3[t][row][c<18] fp32 = 9.4 MB (end ~22.6 MB)

typedef int  v4i  __attribute__((ext_vector_type(4)));
typedef int  v16i __attribute__((ext_vector_type(16)));
typedef unsigned long long ull;

__device__ __forceinline__ v4i expand_bits(unsigned bits) {
  v4i a;
  a.x = (int)((( bits        & 15u) * 0x204081u) & 0x01010101u);
  a.y = (int)((((bits >>  4) & 15u) * 0x204081u) & 0x01010101u);
  a.z = (int)((((bits >>  8) & 15u) * 0x204081u) & 0x01010101u);
  a.w = (int)((((bits >> 12) & 15u) * 0x204081u) & 0x01010101u);
  return a;
}

// ---- merged weight prep: W2 digits (bid<2048) | W3 digits (bid>=2048).
// W2: fp32 -> 4 signed-i8 digit planes of llrint(w*2^32), laid out
// [stripe(8)][d(4)][s(16)][h(2)][n(32)][j(16)]; h1 = s*32+h*16+j, h2 = stripe*32+n.
// W3: LDS image [d(4)][c8(8)][h(2)][col(32)][j(16)], 32 KB.
__global__ __launch_bounds__(256) void prep_weights(const float* __restrict__ W2,
    const float* __restrict__ W3, signed char* __restrict__ dig,
    signed char* __restrict__ w3dig)
{
  const int bid = blockIdx.x, tid = threadIdx.x;
  if (bid < 2048) {
    int i = bid * 256 + tid;                      // [0, 524288)
    int j = i & 15, n = (i >> 4) & 31, h = (i >> 9) & 1;
    int s = (i >> 10) & 15, d = (i >> 14) & 3, st = i >> 16;
    int h1 = s * 32 + h * 16 + j;
    int h2 = st * 32 + n;
    float w = W2[h2 * HH1 + h1];
    long long ll = llrint((double)w * 4294967296.0);
    int v = (int)ll;
    signed char d0 = (signed char)(v & 255); v = (v - d0) >> 8;
    signed char d1 = (signed char)(v & 255); v = (v - d1) >> 8;
    signed char d2 = (signed char)(v & 255); v = (v - d2) >> 8;
    signed char d3 = (signed char)v;
    dig[i] = (d == 0) ? d0 : (d == 1) ? d1 : (d == 2) ? d2 : d3;
  } else {
    int i = (bid - 2048) * 256 + tid;             // [0, 32768)
    int j = i & 15, col = (i >> 4) & 31, h = (i >> 9) & 1;
    int c8 = (i >> 10) & 7, d = (i >> 13) & 3;
    int h2 = c8 * 32 + h * 16 + j;
    float w = (col < CC) ? W3[col * HH2 + h2] : 0.0f;
    long long ll = llrint((double)w * 4294967296.0);
    int v = (int)ll;
    signed char d0 = (signed char)(v & 255); v = (v - d0) >> 8;
    signed char d1 = (signed char)(v & 255); v = (v - d1) >> 8;
    signed char d2 = (signed char)(v & 255); v = (v - d2) >> 8;
    signed char d3 = (signed char)v;
    w3dig[i] = (d == 0) ? d0 : (d == 1) ? d1 : (d == 2) ? d2 : d3;
  }
}

// ---- phase A: bit-exact layer-1 spike masks for all (row,t). One block/row.
// masks layout: [row][chunk(4)][word(8)][t32]  (element = row*1024 + c*256 + w*32 + t&31)
__global__ __launch_bounds__(256) void phase_s1(const float* __restrict__ x,
    const float* __restrict__ W1, const float* __restrict__ b1,
    ull* __restrict__ masks)
{
  __shared__ float xrow[TT];
  int row = blockIdx.x, tid = threadIdx.x, wv = tid >> 6, lane = tid & 63;
  for (int i = tid; i < TT; i += 256) xrow[i] = x[row * TT + i];
  const float w1a = W1[tid], w1b = W1[tid + 256];
  const float b1a = b1[tid], b1b = b1[tid + 256];
  float v1a = 0.f, v1b = 0.f;
  __syncthreads();
  for (int t = 0; t < TT; ++t) {
    float xt = xrow[t];
    float iA = __fadd_rn(__fmul_rn(xt, w1a), b1a);
    v1a = __fadd_rn(v1a, iA);
    bool sA = (v1a >= 1.0f);  v1a = sA ? (v1a - 1.0f) : v1a;
    float iB = __fadd_rn(__fmul_rn(xt, w1b), b1b);
    v1b = __fadd_rn(v1b, iB);
    bool sB = (v1b >= 1.0f);  v1b = sB ? (v1b - 1.0f) : v1b;
    ull mA = __ballot(sA);
    ull mB = __ballot(sB);
    if (lane == 0) {
      ull* p = masks + (size_t)row * 1024 + (size_t)(t >> 5) * 256 + (t & 31);
      p[(size_t)wv * 32]       = mA;              // word wv    : h1 [64wv, +64)
      p[(size_t)(4 + wv) * 32] = mB;              // word 4+wv  : h1 [256+64wv, +64)
    }
  }
}

// ---- fused layer 2, t-as-M-dimension: barrier-free main loop (R5, verified 72 us).
// Block = 512 thr (8 waves), LDS = Bl only (64 KB). Wave task = 2 adjacent
// batch rows (r1, r2 = r1+1) x all 128 t; 2 tasks per wave (tau).
// Per 32-t chunk: A-tile rows are TIMESTEPS; each q-load feeds BOTH tiles
// (P/Q pairing halves LDS port traffic - load-bearing, do not drop).
// v2 scan fully in-register via shfl_xor(32). ~240 regs -> 2 waves/SIMD.
__global__ __launch_bounds__(512, 2) void phase_gemmscan(
    const signed char* __restrict__ Bd, const ull* __restrict__ masks,
    const float* __restrict__ b2, unsigned* __restrict__ masks2)
{
  __shared__ __align__(16) signed char Bl[65536];

  const int bid = blockIdx.x;
  const int rowgrp = bid & 31, stripe = bid >> 5; // same-rowgrp -> same XCD
  const int tid = threadIdx.x, lane = tid & 63, wv = tid >> 6;
  const int half = lane >> 5, l31 = lane & 31;

  {
    const uint4* src = (const uint4*)(Bd + (size_t)stripe * 65536);
    uint4* dst = (uint4*)Bl;
#pragma unroll
    for (int i = 0; i < 8; ++i) dst[tid + 512 * i] = src[tid + 512 * i];
  }

  const signed char* bbase = Bl + half * 512 + l31 * 16;
  const float b2r = b2[stripe * 32 + l31];
  const unsigned hsh = half * 16;

  // A-row i = l31 -> t_local. tile1: lo-half regs get t 0..15 in order.
  const int tp1 = (l31 & 3) + ((l31 >> 3) << 2) + ((l31 & 4) ? 16 : 0);
  const int tp2 = tp1 ^ 16;                       // tile2: inverted halves

  __syncthreads();                                // Bl ready (only barrier)

  // de-phase stagger: waves 4-7 share SIMDs with waves 0-3.
  if (wv & 4) {
    __builtin_amdgcn_s_sleep(15);
    __builtin_amdgcn_s_sleep(15);
  }

  for (int tau = 0; tau < 2; ++tau) {
    const int pr = wv + 8 * tau;                  // pair 0..15
    const int r1 = rowgrp * 32 + 2 * pr;
    const ull* mb1 = masks + (size_t)r1 * 1024;
    const ull* mb2 = mb1 + 1024;                  // row r1+1
    unsigned* m2t = masks2 + (size_t)stripe * (TT * BB);
    float v2 = 0.f;                               // lo: r1 state, hi: r2 state

    ull wP[8], wQ[8], wPn[8], wQn[8];
#pragma unroll
    for (int k = 0; k < 8; ++k) {
      wP[k] = mb1[k * 32 + tp1];
      wQ[k] = mb2[k * 32 + tp2];
    }

#pragma unroll
    for (int c = 0; c < 4; ++c) {
      if (c < 3) {                                // prefetch next chunk's masks
#pragma unroll
        for (int k = 0; k < 8; ++k) {
          wPn[k] = mb1[(c + 1) * 256 + k * 32 + tp1];
          wQn[k] = mb2[(c + 1) * 256 + k * 32 + tp2];
        }
      }

      v16i aP[4], aQ[4];
#pragma unroll
      for (int d = 0; d < 4; ++d) {
        aP[d] = (v16i){0,0,0,0,0,0,0,0,0,0,0,0,0,0,0,0};
        aQ[d] = (v16i){0,0,0,0,0,0,0,0,0,0,0,0,0,0,0,0};
      }
      __builtin_amdgcn_s_setprio(1);
#pragma unroll
      for (int s = 0; s < 16; ++s) {
        v4i q0 = *(const v4i*)(bbase + (0 * 16 + s) * 1024);
        v4i q1 = *(const v4i*)(bbase + (1 * 16 + s) * 1024);
        v4i q2 = *(const v4i*)(bbase + (2 * 16 + s) * 1024);
        v4i q3 = *(const v4i*)(bbase + (3 * 16 + s) * 1024);
        unsigned shift = ((s & 1) << 5) + hsh;
        v4i eP = expand_bits((unsigned)(wP[s >> 1] >> shift) & 0xFFFFu);
        v4i eQ = expand_bits((unsigned)(wQ[s >> 1] >> shift) & 0xFFFFu);
        aP[0] = __builtin_amdgcn_mfma_i32_32x32x32_i8(eP, q0, aP[0], 0, 0, 0);
        aQ[0] = __builtin_amdgcn_mfma_i32_32x32x32_i8(eQ, q0, aQ[0], 0, 0, 0);
        aP[1] = __builtin_amdgcn_mfma_i32_32x32x32_i8(eP, q1, aP[1], 0, 0, 0);
        aQ[1] = __builtin_amdgcn_mfma_i32_32x32x32_i8(eQ, q1, aQ[1], 0, 0, 0);
        aP[2] = __builtin_amdgcn_mfma_i32_32x32x32_i8(eP, q2, aP[2], 0, 0, 0);
        aQ[2] = __builtin_amdgcn_mfma_i32_32x32x32_i8(eQ, q2, aQ[2], 0, 0, 0);
        aP[3] = __builtin_amdgcn_mfma_i32_32x32x32_i8(eP, q3, aP[3], 0, 0, 0);
        aQ[3] = __builtin_amdgcn_mfma_i32_32x32x32_i8(eQ, q3, aQ[3], 0, 0, 0);
      }
      __builtin_amdgcn_s_setprio(0);

      // exact digit fold -> one f32 rounding (bit-identical).
      // dP[r]: tile1 value at t_local = r + 16*half; dQ[r]: r + 16*(1-half).
      float dP[16], dQ[16];
#pragma unroll
      for (int r = 0; r < 16; ++r) {
        int sloP = aP[0][r] + (aP[1][r] << 8);
        int shiP = aP[2][r] + (aP[3][r] << 8);
        double ssP = fma((double)shiP, 65536.0, (double)sloP);  // exact
        dP[r] = (float)(ssP * 0x1p-32);                         // one rounding
        int sloQ = aQ[0][r] + (aQ[1][r] << 8);
        int shiQ = aQ[2][r] + (aQ[3][r] << 8);
        double ssQ = fma((double)shiQ, 65536.0, (double)sloQ);
        dQ[r] = (float)(ssQ * 0x1p-32);
      }

      // ---- in-register v2 scan of 32 t (exact order t = tb..tb+31)
      const int tb = c * 32;
      // phase 1: lo lanes scan r1 (dP), hi lanes scan r2 (dQ); t = tb + r
#pragma unroll
      for (int r = 0; r < 16; ++r) {
        float val = half ? dQ[r] : dP[r];
        float i2 = __fadd_rn(val, b2r);
        v2 = __fadd_rn(v2, i2);
        bool s2 = (v2 >= 1.0f);  v2 = s2 ? (v2 - 1.0f) : v2;
        ull m = __ballot(s2);                     // lo32: r1 word, hi32: r2
        if (lane == 0)
          *(ull*)(m2t + (size_t)(tb + r) * BB + r1) = m;
      }
      v2 = __shfl_xor(v2, 32);                    // exchange row states
      // phase 2: lo lanes scan r2 (dQ), hi lanes scan r1 (dP); t = tb+16+r
#pragma unroll
      for (int r = 0; r < 16; ++r) {
        float val = half ? dP[r] : dQ[r];
        float i2 = __fadd_rn(val, b2r);
        v2 = __fadd_rn(v2, i2);
        bool s2 = (v2 >= 1.0f);  v2 = s2 ? (v2 - 1.0f) : v2;
        ull m = __ballot(s2);                     // lo32: r2 word, hi32: r1
        if (lane == 0)
          *(ull*)(m2t + (size_t)(tb + 16 + r) * BB + r1) = (m >> 32) | (m << 32);
      }
      v2 = __shfl_xor(v2, 32);                    // restore arrangement

      if (c < 3) {
#pragma unroll
        for (int k = 0; k < 8; ++k) { wP[k] = wPn[k]; wQ[k] = wQn[k]; }
      }
    }
  }
}

// ---- layer 3: D3[t] = S2[t] @ W3^T, exact i8 MFMA. Block: 32 rows x 4 t.
// masks2 layout is [stripe][t][row] u32.
__global__ __launch_bounds__(256) void phase_l3(const signed char* __restrict__ W3d,
    const unsigned* __restrict__ masks2, float* __restrict__ D3)
{
  __shared__ __align__(16) signed char Bl[32768];
  const int bid = blockIdx.x;
  const int rowtile = bid & 31, tgrp = bid >> 5;
  const int tid = threadIdx.x, lane = tid & 63, wv = tid >> 6;
  const int half = lane >> 5;
  const int t = tgrp * 4 + wv;
  const int row = rowtile * 32 + (lane & 31);

  {
    const uint4* src = (const uint4*)W3d;
    uint4* dst = (uint4*)Bl;
#pragma unroll
    for (int i = 0; i < 8; ++i) dst[tid + 256 * i] = src[tid + 256 * i];
  }

  unsigned words[8];
  {
    const unsigned* mp = masks2 + (size_t)t * BB + row;
#pragma unroll
    for (int k = 0; k < 8; ++k) words[k] = mp[(size_t)k * (TT * BB)];
  }
  __syncthreads();

  const signed char* bbase = Bl + half * 512 + (lane & 31) * 16;
  v16i acc[4];
#pragma unroll
  for (int d = 0; d < 4; ++d) acc[d] = (v16i){0,0,0,0,0,0,0,0,0,0,0,0,0,0,0,0};

#pragma unroll
  for (int c8 = 0; c8 < 8; ++c8) {
    v4i a = expand_bits((words[c8] >> (half * 16)) & 0xFFFFu);
#pragma unroll
    for (int d = 0; d < 4; ++d) {
      v4i b = *(const v4i*)(bbase + ((d * 8 + c8) * 2) * 512);
      acc[d] = __builtin_amdgcn_mfma_i32_32x32x32_i8(a, b, acc[d], 0, 0, 0);
    }
  }

  const int col = lane & 31;
#pragma unroll
  for (int r = 0; r < 16; ++r) {
    int slo = acc[0][r] + (acc[1][r] << 8);
    int shi = acc[2][r] + (acc[3][r] << 8);
    double ss = fma((double)shi, 65536.0, (double)slo);
    float d3v = (float)(ss * 0x1p-32);
    int rowl = (r & 3) + 8 * (r >> 2) + 4 * half;
    int grow = rowtile * 32 + rowl;
    if (col < CC) D3[((size_t)t * BB + grow) * CC + col] = d3v;
  }
}

// ---- v3/acc scan + output. thread=(row,c). FIX (rule #20): the old 4-deep
// ring indexed buf[t&3] with runtime t in a rolled loop -> scratch round-trip
// every iteration. Now: 16-deep cur/nxt windows, ALL indices static inside
// #pragma unroll -> pure registers, 16 loads in flight. Grid 144x128 doubles
// CU coverage (was 72 blocks = 28% of CUs).
__global__ __launch_bounds__(128) void phase_v3(const float* __restrict__ D3,
    const float* __restrict__ b3, float* __restrict__ out)
{
  int g = blockIdx.x * 128 + threadIdx.x;         // [0, 18432)
  int row = g / CC, c = g - row * CC; (void)row;
  const float b3r = b3[c];
  float v3 = 0.f, acc = 0.f;
  float cur[16], nxt[16];
#pragma unroll
  for (int p = 0; p < 16; ++p) cur[p] = D3[(size_t)p * (BB * CC) + g];
  for (int w = 0; w < 8; ++w) {
    if (w < 7) {
#pragma unroll
      for (int p = 0; p < 16; ++p)
        nxt[p] = D3[(size_t)((w + 1) * 16 + p) * (BB * CC) + g];
    }
#pragma unroll
    for (int p = 0; p < 16; ++p) {
      float i3 = __fadd_rn(cur[p], b3r);
      v3 = __fadd_rn(v3, i3);
      bool s3 = (v3 >= 1.0f);  v3 = s3 ? (v3 - 1.0f) : v3;
      acc = __fadd_rn(acc, s3 ? 1.0f : 0.0f);
    }
#pragma unroll
    for (int p = 0; p < 16; ++p) cur[p] = nxt[p];
  }
  out[g] = acc * (1.0f / TT);
}

extern "C" void kernel_launch(void* const* d_in, const int* in_sizes, int n_in,
                              void* d_out, int out_size, void* d_ws, size_t ws_size,
                              hipStream_t stream)
{
  (void)in_sizes; (void)n_in; (void)out_size; (void)ws_size;
  const float* x  = (const float*)d_in[0];
  const float* W1 = (const float*)d_in[1];
  const float* b1 = (const float*)d_in[2];
  const float* W2 = (const float*)d_in[3];
  const float* b2 = (const float*)d_in[4];
  const float* W3 = (const float*)d_in[5];
  const float* b3 = (const float*)d_in[6];
  // d_in[7] = repeat (structurally 1 for this problem shape)
  float* out = (float*)d_out;
  char*  ws  = (char*)d_ws;

  signed char* dig    = (signed char*)(ws + WS_DIG);
  signed char* w3dig  = (signed char*)(ws + WS_W3D);
  ull*         masks  = (ull*)(ws + WS_MASK);
  unsigned*    masks2 = (unsigned*)(ws + WS_MASK2);
  float*       D3     = (float*)(ws + WS_D3);

  prep_weights<<<2176, 256, 0, stream>>>(W2, W3, dig, w3dig);
  phase_s1<<<1024, 256, 0, stream>>>(x, W1, b1, masks);
  phase_gemmscan<<<256, 512, 0, stream>>>(dig, masks, b2, masks2);
  phase_l3<<<1024, 256, 0, stream>>>(w3dig, masks2, D3);
  phase_v3<<<144, 128, 0, stream>>>(D3, b3, out);
}